// Round 15
// baseline (222.976 us; speedup 1.0000x reference)
//
#include <hip/hip_runtime.h>
#include <math.h>

#define BB 2
#define TT 8
#define NN 512
#define HH 64
#define NC 10

typedef unsigned char uchar;

__device__ __forceinline__ float elu1(float v){ return v > 0.f ? v : expm1f(v); }
__device__ __forceinline__ float sigm(float v){ return 1.f/(1.f+expf(-v)); }

// ---------------- K0: masks M0/M1; zero hseq; AB; Whh k-major transposes ------
__global__ __launch_bounds__(256) void k_mask(
    const float* __restrict__ dW, const float* __restrict__ sadj,
    uchar* __restrict__ M0, uchar* __restrict__ M1,
    float* __restrict__ hseq,
    const float* __restrict__ att1, const float* __restrict__ Wr1,
    const float* __restrict__ Wl1, float* __restrict__ AB,
    const float* __restrict__ Whh0, const float* __restrict__ Whh1,
    float4* __restrict__ WT4)
{
    __shared__ float tr[64][65];
    int bx = blockIdx.x, by = blockIdx.y;
    int tid = threadIdx.x;
    if (blockIdx.z == 1){
        int idx = (by*8 + bx)*256 + tid;           // 0..16383, need 8192
        if (idx < 2*4096){
            int m = idx >> 12, r = idx & 4095;
            int k = r >> 6, gg = r & 63;
            const float* W = m ? Whh1 : Whh0;
            float4 o;
            o.x = W[k*192 + gg];
            o.y = W[k*192 + 64 + gg];
            o.z = W[k*192 + 128 + gg];
            o.w = 0.f;
            WT4[(size_t)m*4096 + r] = o;
        }
        return;
    }
    int i0 = by*64, j0 = bx*64;
    #pragma unroll
    for (int q = 0; q < 4; ++q){
        int r = (tid >> 4) + 16*q, c4 = tid & 15;
        float4 v = *(const float4*)&dW[(size_t)(j0+r)*NN + i0 + 4*c4];
        tr[r][4*c4+0] = v.x; tr[r][4*c4+1] = v.y;
        tr[r][4*c4+2] = v.z; tr[r][4*c4+3] = v.w;
    }
    __syncthreads();
    #pragma unroll
    for (int q = 0; q < 4; ++q){
        int row = (tid >> 4) + 16*q, c4 = tid & 15;
        int i = i0 + row, j = j0 + 4*c4;
        float4 d  = *(const float4*)&dW[(size_t)i*NN + j];
        float4 sa = *(const float4*)&sadj[(size_t)i*NN + j];
        uchar4 m0, m1;
        float dd0 = d.x + tr[4*c4+0][row];
        float dd1 = d.y + tr[4*c4+1][row];
        float dd2 = d.z + tr[4*c4+2][row];
        float dd3 = d.w + tr[4*c4+3][row];
        m0.x = (sa.x > 0.f) || (i == j+0);
        m0.y = (sa.y > 0.f) || (i == j+1);
        m0.z = (sa.z > 0.f) || (i == j+2);
        m0.w = (sa.w > 0.f) || (i == j+3);
        m1.x = m0.x || (dd0 > 0.f);
        m1.y = m0.y || (dd1 > 0.f);
        m1.z = m0.z || (dd2 > 0.f);
        m1.w = m0.w || (dd3 > 0.f);
        *(uchar4*)&M0[(size_t)i*NN + j] = m0;
        *(uchar4*)&M1[(size_t)i*NN + j] = m1;
    }
    int flat = (by*8 + bx)*256 + tid;
    if (flat < BB*TT*HH) hseq[flat] = 0.f;
    if (bx == 0 && by == 0 && tid < 8){
        int h = tid & 3;
        const float* W = (tid < 4) ? Wr1 : Wl1;
        float s = 0.f;
        for (int c = 0; c < 16; ++c) s += att1[h*16+c]*W[h*16+c];
        AB[tid] = s;
    }
}

// ---------------- K1: GAT1+lin2, 8 nodes/vblock x 4 vblocks (r14) --------------
__global__ __launch_bounds__(512) void k_gat1f(
    const float* __restrict__ x_seq, const uchar* __restrict__ M0,
    const uchar* __restrict__ M1,
    const float* __restrict__ Wl, const float* __restrict__ Wr,
    const float* __restrict__ att, const float* __restrict__ bias,
    const float* __restrict__ AB,
    const float* __restrict__ Wl2, const float* __restrict__ Wr2,
    const float* __restrict__ att2,
    float* __restrict__ xl2, float* __restrict__ xr2,
    float* __restrict__ ui, float* __restrict__ vj)
{
    __shared__ float x_s[NN];
    __shared__ float S_s[8][4];
    __shared__ float h_s[8][HH];
    __shared__ float Wl2_s[64*64];
    __shared__ float Wr2_s[64*64];
    int tid = threadIdx.x;
    #pragma unroll
    for (int q = 0; q < 2; ++q){
        int idx = q*512 + tid;
        ((float4*)Wl2_s)[idx] = ((const float4*)Wl2)[idx];
        ((float4*)Wr2_s)[idx] = ((const float4*)Wr2)[idx];
    }
    int w = tid >> 6, jl = tid & 63;
    for (int s = 0; s < 4; ++s){
        int vb = blockIdx.x*4 + s;           // 0..1023
        int bt = vb >> 6, it = vb & 63;
        int i0v = it*8;
        int t = bt & 7;
        const uchar* M = t ? M1 : M0;
        __syncthreads();                     // protect x_s/h_s reuse (+Wl2 1st iter)
        x_s[tid] = x_seq[bt*NN + tid];
        __syncthreads();
        int i = i0v + w;
        float xi = x_s[i];
        const uchar* Mrow = M + (size_t)i*NN;
        float xj[8], msk[8];
        #pragma unroll
        for (int jj = 0; jj < 8; ++jj){
            int j = jj*64 + jl;
            xj[jj] = x_s[j];
            msk[jj] = Mrow[j] ? 1.f : 0.f;
        }
        float sw[4] = {0,0,0,0}, swx[4] = {0,0,0,0};
        for (int h = 0; h < 4; ++h){
            float acc[8] = {0,0,0,0,0,0,0,0};
            #pragma unroll
            for (int c = 0; c < 16; ++c){
                int hc = h*16 + c;
                float wl = Wl[hc];
                float q  = 0.4f * att[hc];
                float pr = xi * Wr[hc];
                #pragma unroll
                for (int jj = 0; jj < 8; ++jj){
                    float sv = fmaf(xj[jj], wl, pr);
                    acc[jj] = fmaf(q, fabsf(sv), acc[jj]);
                }
            }
            float lin = 0.6f * xi * AB[h];
            float al6 = 0.6f * AB[4+h];
            #pragma unroll
            for (int jj = 0; jj < 8; ++jj){
                float e = acc[jj] + fmaf(al6, xj[jj], lin);
                float ww = msk[jj] * __expf(e);
                sw[h] += ww;
                swx[h] = fmaf(ww, xj[jj], swx[h]);
            }
        }
        #pragma unroll
        for (int off = 32; off; off >>= 1){
            #pragma unroll
            for (int h = 0; h < 4; ++h){
                sw[h]  += __shfl_down(sw[h],  off);
                swx[h] += __shfl_down(swx[h], off);
            }
        }
        if (jl == 0){
            #pragma unroll
            for (int h = 0; h < 4; ++h) S_s[w][h] = swx[h] / sw[h];
        }
        __syncthreads();
        {
            int hc = tid & 63, row = tid >> 6;
            float v = S_s[row][hc >> 4] * Wl[hc] + bias[hc];
            h_s[row][hc] = elu1(v);
        }
        __syncthreads();
        {
            int c = tid & 63, row = tid >> 6;
            float al = 0.f, ar = 0.f;
            #pragma unroll 8
            for (int k = 0; k < 64; ++k){
                float hv = h_s[row][k];
                al = fmaf(hv, Wl2_s[k*64 + c], al);
                ar = fmaf(hv, Wr2_s[k*64 + c], ar);
            }
            size_t ridx = (size_t)(bt*NN + i0v + row);
            xl2[ridx*HH + c] = al;
            xr2[ridx*HH + c] = ar;
            float a2 = att2[c];
            float pu = a2 * ar, pv = a2 * al;
            #pragma unroll
            for (int off = 32; off; off >>= 1){
                pu += __shfl_down(pu, off);
                pv += __shfl_down(pv, off);
            }
            if (c == 0){ ui[ridx] = pu; vj[ridx] = pv; }
        }
    }
}

// ---------------- K2: fused GAT2 — 2 blocks/CU version -------------------------
// r14 diagnosis: 41.4us @ Occupancy 16% (108KB LDS -> 1 block/CU), VALUBusy 47%,
// ~53% stall with nothing to hide latency behind. Fix: i-tile 32->16 (grid 512,
// 2 blocks/CU = 16 waves), j-tile 256->128 (4 tiles), LDS 108KB -> ~45KB.
// Same total work; per-thread e[2][2]/acc[2][8], float2 wT accesses.
__global__ __launch_bounds__(512) void k_gat2(
    const float* __restrict__ xl2, const float* __restrict__ xr2,
    const uchar* __restrict__ M0, const uchar* __restrict__ M1,
    const float* __restrict__ att, const float* __restrict__ ui,
    const float* __restrict__ vj, const float* __restrict__ bias,
    float* __restrict__ hseq)
{
    __shared__ float xl_s[128][68];   // 34816 B (reused as reduce scratch)
    __shared__ float wT_s[128][18];   // 9216 B   wT[j][i_local], i_local<16
    __shared__ float v_s[128];
    __shared__ float z_s[16];

    int bt = blockIdx.y, t = bt & 7;
    int i0 = blockIdx.x * 16;
    int base = bt * NN;
    int tid = threadIdx.x;
    const uchar* M = t ? M1 : M0;

    int ig = __builtin_amdgcn_readfirstlane(tid >> 6);  // wave id, uniform
    int jg = tid & 63;
    int ln = jg;
    int ig2 = ln >> 3, cg2 = ln & 7;

    const float* xrp0 = xr2 + (size_t)(base + i0 + ig*2 + 0)*HH;
    const float* xrp1 = xr2 + (size_t)(base + i0 + ig*2 + 1)*HH;
    float u0 = 0.6f*ui[base + i0 + ig*2 + 0];
    float u1 = 0.6f*ui[base + i0 + ig*2 + 1];

    float zreg[2] = {0.f, 0.f};
    float acc[2][8];
    #pragma unroll
    for (int a = 0; a < 2; ++a)
        #pragma unroll
        for (int r = 0; r < 8; ++r) acc[a][r] = 0.f;

    for (int tile = 0; tile < 4; ++tile){
        int j0 = tile * 128;
        __syncthreads();                   // xl_s/wT_s free from prev agg
        #pragma unroll
        for (int q = 0; q < 4; ++q){
            int idx = q*512 + tid;         // 0..2047
            int row = idx >> 4, c4 = idx & 15;
            ((float4*)&xl_s[row][0])[c4] = ((const float4*)&xl2[(size_t)(base+j0+row)*HH])[c4];
        }
        if (tid < 128) v_s[tid] = vj[base + j0 + tid];
        __syncthreads();
        // ---- scores: e[2i][2j], j = jj*64 + jg ----
        float e[2][2];
        #pragma unroll
        for (int jj = 0; jj < 2; ++jj){
            float vv = 0.6f * v_s[jj*64 + jg];
            e[0][jj] = u0 + vv; e[1][jj] = u1 + vv;
        }
        #pragma unroll 4
        for (int c4 = 0; c4 < 16; ++c4){
            float4 a4 = *(const float4*)&att[c4*4];
            float qk[4];
            qk[0] = 0.4f*a4.x; qk[1] = 0.4f*a4.y; qk[2] = 0.4f*a4.z; qk[3] = 0.4f*a4.w;
            float rr[2][4];                           // uniform (scalar) loads
            *(float4*)rr[0] = *(const float4*)&xrp0[c4*4];
            *(float4*)rr[1] = *(const float4*)&xrp1[c4*4];
            float xlv[2][4];
            #pragma unroll
            for (int jj = 0; jj < 2; ++jj)
                *(float4*)xlv[jj] = ((const float4*)&xl_s[jj*64+jg][0])[c4];
            #pragma unroll
            for (int jj = 0; jj < 2; ++jj)
                #pragma unroll
                for (int k = 0; k < 4; ++k){
                    float xc = xlv[jj][k];
                    e[0][jj] = fmaf(qk[k], fabsf(rr[0][k] + xc), e[0][jj]);
                    e[1][jj] = fmaf(qk[k], fabsf(rr[1][k] + xc), e[1][jj]);
                }
        }
        // ---- mask + exp -> wT tile, z accum ----
        #pragma unroll
        for (int jj = 0; jj < 2; ++jj){
            int j = jj*64 + jg;
            const uchar* mp = &M[(size_t)(i0 + ig*2)*NN + j0 + j];
            float w0 = mp[0]  ? __expf(e[0][jj]) : 0.f;
            float w1 = mp[NN] ? __expf(e[1][jj]) : 0.f;
            zreg[0] += w0; zreg[1] += w1;
            float2 wq; wq.x = w0; wq.y = w1;
            *(float2*)&wT_s[j][ig*2] = wq;
        }
        __syncthreads();
        // ---- agg: wave ig handles j in [ig*16, ig*16+16) of this tile ----
        #pragma unroll 4
        for (int jj = 0; jj < 16; ++jj){
            int j = ig*16 + jj;
            float2 w2 = *(const float2*)&wT_s[j][ig2*2];
            float xa[8];
            *(float4*)&xa[0] = ((const float4*)&xl_s[j][0])[cg2*2+0];
            *(float4*)&xa[4] = ((const float4*)&xl_s[j][0])[cg2*2+1];
            #pragma unroll
            for (int r = 0; r < 8; ++r){
                acc[0][r] = fmaf(w2.x, xa[r], acc[0][r]);
                acc[1][r] = fmaf(w2.y, xa[r], acc[1][r]);
            }
        }
    }
    __syncthreads();
    // z reduce over full wave
    #pragma unroll
    for (int off = 32; off; off >>= 1){
        zreg[0] += __shfl_down(zreg[0], off);
        zreg[1] += __shfl_down(zreg[1], off);
    }
    if (jg == 0){ z_s[ig*2+0] = zreg[0]; z_s[ig*2+1] = zreg[1]; }
    // cross-wave acc reduce: waves 1-7 dump to scratch (reuse xl_s: 8704 floats)
    float* scratch = &xl_s[0][0];   // need 16*448 = 7168 floats < 8704
    if (ig > 0){
        #pragma unroll
        for (int a = 0; a < 2; ++a)
            #pragma unroll
            for (int r = 0; r < 8; ++r)
                scratch[(a*8+r)*448 + (ig-1)*64 + ln] = acc[a][r];
    }
    __syncthreads();
    if (ig == 0){
        float pm[8];
        #pragma unroll
        for (int r = 0; r < 8; ++r) pm[r] = 0.f;
        #pragma unroll
        for (int a = 0; a < 2; ++a){
            float rz = 1.f / z_s[ig2*2 + a];
            #pragma unroll
            for (int r = 0; r < 8; ++r){
                float s = acc[a][r];
                #pragma unroll
                for (int w = 0; w < 7; ++w)
                    s += scratch[(a*8+r)*448 + w*64 + ln];
                float h = elu1(s*rz + bias[cg2*8 + r]);
                pm[r] += h;
            }
        }
        // reduce node-partials over the 8 ig2 groups -> lanes 0..7
        #pragma unroll
        for (int off = 32; off >= 8; off >>= 1){
            #pragma unroll
            for (int r = 0; r < 8; ++r) pm[r] += __shfl_down(pm[r], off);
        }
        if (ig2 == 0){
            #pragma unroll
            for (int r = 0; r < 8; ++r)
                atomicAdd(&hseq[bt*HH + cg2*8 + r], pm[r] * (1.f/(float)NN));
        }
    }
}

// ---------------- K3: GRU x2 — Wih LDS-staged + quad-vectorized (r12) ----------
__global__ __launch_bounds__(256, 1) void k_gru2(
    const float* __restrict__ hseq, const float* __restrict__ Wih0,
    const float* __restrict__ bih0, const float4* __restrict__ WT4,
    const float* __restrict__ bhh0, const float* __restrict__ Wih1,
    const float* __restrict__ bih1, const float* __restrict__ bhh1,
    const float* __restrict__ lamp, const float* __restrict__ attn_W,
    const float* __restrict__ attn_b, const float* __restrict__ W1,
    const float* __restrict__ b1, const float* __restrict__ ln_g,
    const float* __restrict__ ln_b, const float* __restrict__ W2,
    const float* __restrict__ b2, float* __restrict__ out)
{
    __shared__ float wih0_s[64*192];         // 49152 B
    __shared__ float wih1_s[64*192];         // 49152 B
    __shared__ float gi_s[BB*TT*192];        // 12288 B
    __shared__ float hs_s[BB*TT*HH];         // 4096 B
    __shared__ float y_s[BB*TT*HH];          // 4096 B
    __shared__ float part_s[2][BB][2][3][HH];// 6144 B (parity double-buffer)
    __shared__ float sc_s[BB][TT], at_s[BB][TT];
    __shared__ float fin_s[BB][HH], z_s[BB][HH], g_s[BB][HH];
    __shared__ float mu_s[BB], iv_s[BB];
    int tid = threadIdx.x;
    int wave = tid >> 6, ln = tid & 63;
    int b = wave >> 1, half = wave & 1;

    // Issue Wih staging FIRST: 2 x 12 independent coalesced float4 loads/thread.
    #pragma unroll
    for (int i = 0; i < 12; ++i){
        int idx = i*256 + tid;               // 0..3071 float4
        ((float4*)wih0_s)[idx] = ((const float4*)Wih0)[idx];
        ((float4*)wih1_s)[idx] = ((const float4*)Wih1)[idx];
    }
    // layer-0 Whh half-slice -> registers, lane-coalesced (k-major WT4)
    float wx[32], wy[32], wz[32];
    #pragma unroll
    for (int k = 0; k < 32; ++k){
        float4 w4 = WT4[(half*32 + k)*64 + ln];
        wx[k] = w4.x; wy[k] = w4.y; wz[k] = w4.z;
    }
    ((float4*)hs_s)[tid] = ((const float4*)hseq)[tid];   // 1024 floats = 256 f4
    __syncthreads();
    // gi0 = hseq @ Wih0 + bih0 -- quad-vectorized: 768 output-quads, 3/thread
    #pragma unroll
    for (int o = 0; o < 3; ++o){
        int idx4 = o*256 + tid;              // 0..767
        int bt = idx4 / 48, q = idx4 % 48;   // outputs g = 4q..4q+3
        float4 a4 = ((const float4*)bih0)[q];
        const float* hr = &hs_s[bt*HH];
        #pragma unroll 4
        for (int k = 0; k < HH; ++k){
            float hk = hr[k];
            float4 w4 = ((const float4*)&wih0_s[k*192])[q];
            a4.x = fmaf(hk, w4.x, a4.x);
            a4.y = fmaf(hk, w4.y, a4.y);
            a4.z = fmaf(hk, w4.z, a4.z);
            a4.w = fmaf(hk, w4.w, a4.w);
        }
        ((float4*)&gi_s[bt*192])[q] = a4;
    }
    __syncthreads();
    // ---- layer 0: 1 barrier/step ----
    {
        float bhr = bhh0[ln], bhz = bhh0[64+ln], bhn = bhh0[128+ln];
        float h = 0.f;
        for (int t = 0; t < TT; ++t){
            float pr = 0.f, pz = 0.f, pn = 0.f;
            #pragma unroll
            for (int k = 0; k < 32; ++k){
                float hk = __shfl(h, half*32 + k);
                pr = fmaf(wx[k], hk, pr);
                pz = fmaf(wy[k], hk, pz);
                pn = fmaf(wz[k], hk, pn);
            }
            int pc = t & 1;
            part_s[pc][b][half][0][ln] = pr;
            part_s[pc][b][half][1][ln] = pz;
            part_s[pc][b][half][2][ln] = pn;
            __syncthreads();
            float ghr = pr + part_s[pc][b][1-half][0][ln] + bhr;
            float ghz = pz + part_s[pc][b][1-half][1][ln] + bhz;
            float ghn = pn + part_s[pc][b][1-half][2][ln] + bhn;
            const float* gi = &gi_s[(b*TT+t)*192];
            float r = sigm(gi[ln] + ghr);
            float z = sigm(gi[64+ln] + ghz);
            float n = tanhf(gi[128+ln] + r*ghn);
            h = (1.f - z)*n + z*h;
            if (half == 0) y_s[(b*TT+t)*HH + ln] = h;
        }
    }
    // reload Whh weights for layer 1 (coalesced)
    #pragma unroll
    for (int k = 0; k < 32; ++k){
        float4 w4 = WT4[4096 + (half*32 + k)*64 + ln];
        wx[k] = w4.x; wy[k] = w4.y; wz[k] = w4.z;
    }
    __syncthreads();                          // y_s complete
    // gi1 = y @ Wih1 + bih1 -- quad-vectorized
    #pragma unroll
    for (int o = 0; o < 3; ++o){
        int idx4 = o*256 + tid;
        int bt = idx4 / 48, q = idx4 % 48;
        float4 a4 = ((const float4*)bih1)[q];
        const float* yr = &y_s[bt*HH];
        #pragma unroll 4
        for (int k = 0; k < HH; ++k){
            float yk = yr[k];
            float4 w4 = ((const float4*)&wih1_s[k*192])[q];
            a4.x = fmaf(yk, w4.x, a4.x);
            a4.y = fmaf(yk, w4.y, a4.y);
            a4.z = fmaf(yk, w4.z, a4.z);
            a4.w = fmaf(yk, w4.w, a4.w);
        }
        ((float4*)&gi_s[bt*192])[q] = a4;
    }
    __syncthreads();
    // ---- layer 1: 1 barrier/step ----
    {
        float bhr = bhh1[ln], bhz = bhh1[64+ln], bhn = bhh1[128+ln];
        float h = 0.f;
        for (int t = 0; t < TT; ++t){
            float pr = 0.f, pz = 0.f, pn = 0.f;
            #pragma unroll
            for (int k = 0; k < 32; ++k){
                float hk = __shfl(h, half*32 + k);
                pr = fmaf(wx[k], hk, pr);
                pz = fmaf(wy[k], hk, pz);
                pn = fmaf(wz[k], hk, pn);
            }
            int pc = t & 1;
            part_s[pc][b][half][0][ln] = pr;
            part_s[pc][b][half][1][ln] = pz;
            part_s[pc][b][half][2][ln] = pn;
            __syncthreads();
            float ghr = pr + part_s[pc][b][1-half][0][ln] + bhr;
            float ghz = pz + part_s[pc][b][1-half][1][ln] + bhz;
            float ghn = pn + part_s[pc][b][1-half][2][ln] + bhn;
            const float* gi = &gi_s[(b*TT+t)*192];
            float r = sigm(gi[ln] + ghr);
            float z = sigm(gi[64+ln] + ghz);
            float n = tanhf(gi[128+ln] + r*ghn);
            h = (1.f - z)*n + z*h;
            if (half == 0) y_s[(b*TT+t)*HH + ln] = h;
        }
    }
    __syncthreads();
    // ---- head ----
    float lam = fmaxf(lamp[0], 0.01f);
    if (tid < TT) out[BB*NC + tid] = expf(-lam*(float)tid);
    if (tid < BB*TT){
        int bb = tid >> 3, t = tid & 7;
        float s = attn_b[0];
        const float* r = &y_s[(bb*TT+t)*HH];
        for (int h = 0; h < HH; ++h) s += r[h]*attn_W[h];
        sc_s[bb][t] = s;
    }
    __syncthreads();
    if (tid < BB){
        float mx = -INFINITY;
        for (int t = 0; t < TT; ++t) mx = fmaxf(mx, sc_s[tid][t]);
        float se = 0.f;
        for (int t = 0; t < TT; ++t){ float w = expf(sc_s[tid][t]-mx); at_s[tid][t] = w; se += w; }
        for (int t = 0; t < TT; ++t){
            at_s[tid][t] /= se;
            out[BB*NC + TT + tid*TT + t] = at_s[tid][t];
        }
    }
    __syncthreads();
    if (tid < BB*HH){
        int bb = tid >> 6, h = tid & 63;
        float a = 0.f;
        for (int t = 0; t < TT; ++t) a += at_s[bb][t]*y_s[(bb*TT+t)*HH + h];
        fin_s[bb][h] = a;
    }
    __syncthreads();
    if (tid < BB*HH){
        int bb = tid >> 6, h = tid & 63;
        float a = b1[h];
        for (int k = 0; k < HH; ++k) a += fin_s[bb][k]*W1[k*HH+h];
        z_s[bb][h] = a;
    }
    __syncthreads();
    if (tid < BB){
        float mu = 0.f;
        for (int h = 0; h < HH; ++h) mu += z_s[tid][h];
        mu *= (1.f/HH);
        float v = 0.f;
        for (int h = 0; h < HH; ++h){ float d = z_s[tid][h]-mu; v += d*d; }
        v *= (1.f/HH);
        mu_s[tid] = mu; iv_s[tid] = 1.f/sqrtf(v + 1e-5f);
    }
    __syncthreads();
    if (tid < BB*HH){
        int bb = tid >> 6, h = tid & 63;
        float zn = (z_s[bb][h]-mu_s[bb])*iv_s[bb]*ln_g[h] + ln_b[h];
        g_s[bb][h] = 0.5f*zn*(1.f + erff(zn*0.70710678118654752f));
    }
    __syncthreads();
    if (tid < BB*NC){
        int bb = tid / NC, c = tid % NC;
        float a = b2[c];
        for (int k = 0; k < HH; ++k) a += g_s[bb][k]*W2[k*NC+c];
        out[bb*NC + c] = a;
    }
}

extern "C" void kernel_launch(void* const* d_in, const int* in_sizes, int n_in,
                              void* d_out, int out_size, void* d_ws, size_t ws_size,
                              hipStream_t stream)
{
    const float* x_seq = (const float*)d_in[0];
    const float* sadj  = (const float*)d_in[1];
    const float* dynW  = (const float*)d_in[2];
    const float* lamp  = (const float*)d_in[3];
    const float* g1_Wl = (const float*)d_in[4];
    const float* g1_Wr = (const float*)d_in[5];
    const float* g1_att= (const float*)d_in[6];
    const float* g1_b  = (const float*)d_in[7];
    const float* g2_Wl = (const float*)d_in[8];
    const float* g2_Wr = (const float*)d_in[9];
    const float* g2_att= (const float*)d_in[10];
    const float* g2_b  = (const float*)d_in[11];
    const float* Wih0  = (const float*)d_in[12];
    const float* Whh0  = (const float*)d_in[13];
    const float* bih0  = (const float*)d_in[14];
    const float* bhh0  = (const float*)d_in[15];
    const float* Wih1  = (const float*)d_in[16];
    const float* Whh1  = (const float*)d_in[17];
    const float* bih1  = (const float*)d_in[18];
    const float* bhh1  = (const float*)d_in[19];
    const float* attnW = (const float*)d_in[20];
    const float* attnb = (const float*)d_in[21];
    const float* W1    = (const float*)d_in[22];
    const float* b1    = (const float*)d_in[23];
    const float* lng   = (const float*)d_in[24];
    const float* lnb   = (const float*)d_in[25];
    const float* W2    = (const float*)d_in[26];
    const float* b2    = (const float*)d_in[27];
    float* out = (float*)d_out;

    const int RWS = BB*TT*NN*HH;              // 524288
    uchar* M0 = (uchar*)d_ws;                 // 262144 B
    uchar* M1 = M0 + (size_t)NN*NN;           // 262144 B
    float* fb = (float*)(M1 + (size_t)NN*NN);
    float* AB   = fb;                         // 16
    float* ui   = AB   + 16;                  // 8192
    float* vj   = ui   + BB*TT*NN;            // 8192
    float* xl2  = vj   + BB*TT*NN;            // 524288
    float* xr2  = xl2  + RWS;                 // 524288
    float* hseq = xr2  + RWS;                 // 1024
    float4* WT4 = (float4*)(hseq + BB*TT*HH); // 2*4096 float4 = 131072 B
    // total ~4.8 MB

    k_mask <<<dim3(8,8,2), 256, 0, stream>>>(dynW, sadj, M0, M1, hseq, g1_att, g1_Wr, g1_Wl, AB,
                                             Whh0, Whh1, WT4);
    k_gat1f<<<dim3(256), 512, 0, stream>>>(x_seq, M0, M1, g1_Wl, g1_Wr, g1_att, g1_b, AB,
                                           g2_Wl, g2_Wr, g2_att, xl2, xr2, ui, vj);
    k_gat2 <<<dim3(NN/16, BB*TT), 512, 0, stream>>>(xl2, xr2, M0, M1, g2_att, ui, vj, g2_b, hseq);
    k_gru2 <<<1, 256, 0, stream>>>(hseq, Wih0, bih0, WT4, bhh0, Wih1, bih1, bhh1,
                                   lamp, attnW, attnb, W1, b1, lng, lnb, W2, b2, out);
}

// Round 17
// 204.902 us; speedup vs baseline: 1.0882x; 1.0882x over previous
//
#include <hip/hip_runtime.h>
#include <math.h>

#define BB 2
#define TT 8
#define NN 512
#define HH 64
#define NC 10

typedef unsigned char uchar;

__device__ __forceinline__ float elu1(float v){ return v > 0.f ? v : expm1f(v); }
__device__ __forceinline__ float sigm(float v){ return 1.f/(1.f+expf(-v)); }

// ---------------- K0: masks M0/M1; zero hseq; AB; Whh k-major transposes ------
__global__ __launch_bounds__(256) void k_mask(
    const float* __restrict__ dW, const float* __restrict__ sadj,
    uchar* __restrict__ M0, uchar* __restrict__ M1,
    float* __restrict__ hseq,
    const float* __restrict__ att1, const float* __restrict__ Wr1,
    const float* __restrict__ Wl1, float* __restrict__ AB,
    const float* __restrict__ Whh0, const float* __restrict__ Whh1,
    float4* __restrict__ WT4)
{
    __shared__ float tr[64][65];
    int bx = blockIdx.x, by = blockIdx.y;
    int tid = threadIdx.x;
    if (blockIdx.z == 1){
        int idx = (by*8 + bx)*256 + tid;           // 0..16383, need 8192
        if (idx < 2*4096){
            int m = idx >> 12, r = idx & 4095;
            int k = r >> 6, gg = r & 63;
            const float* W = m ? Whh1 : Whh0;
            float4 o;
            o.x = W[k*192 + gg];
            o.y = W[k*192 + 64 + gg];
            o.z = W[k*192 + 128 + gg];
            o.w = 0.f;
            WT4[(size_t)m*4096 + r] = o;
        }
        return;
    }
    int i0 = by*64, j0 = bx*64;
    #pragma unroll
    for (int q = 0; q < 4; ++q){
        int r = (tid >> 4) + 16*q, c4 = tid & 15;
        float4 v = *(const float4*)&dW[(size_t)(j0+r)*NN + i0 + 4*c4];
        tr[r][4*c4+0] = v.x; tr[r][4*c4+1] = v.y;
        tr[r][4*c4+2] = v.z; tr[r][4*c4+3] = v.w;
    }
    __syncthreads();
    #pragma unroll
    for (int q = 0; q < 4; ++q){
        int row = (tid >> 4) + 16*q, c4 = tid & 15;
        int i = i0 + row, j = j0 + 4*c4;
        float4 d  = *(const float4*)&dW[(size_t)i*NN + j];
        float4 sa = *(const float4*)&sadj[(size_t)i*NN + j];
        uchar4 m0, m1;
        float dd0 = d.x + tr[4*c4+0][row];
        float dd1 = d.y + tr[4*c4+1][row];
        float dd2 = d.z + tr[4*c4+2][row];
        float dd3 = d.w + tr[4*c4+3][row];
        m0.x = (sa.x > 0.f) || (i == j+0);
        m0.y = (sa.y > 0.f) || (i == j+1);
        m0.z = (sa.z > 0.f) || (i == j+2);
        m0.w = (sa.w > 0.f) || (i == j+3);
        m1.x = m0.x || (dd0 > 0.f);
        m1.y = m0.y || (dd1 > 0.f);
        m1.z = m0.z || (dd2 > 0.f);
        m1.w = m0.w || (dd3 > 0.f);
        *(uchar4*)&M0[(size_t)i*NN + j] = m0;
        *(uchar4*)&M1[(size_t)i*NN + j] = m1;
    }
    int flat = (by*8 + bx)*256 + tid;
    if (flat < BB*TT*HH) hseq[flat] = 0.f;
    if (bx == 0 && by == 0 && tid < 8){
        int h = tid & 3;
        const float* W = (tid < 4) ? Wr1 : Wl1;
        float s = 0.f;
        for (int c = 0; c < 16; ++c) s += att1[h*16+c]*W[h*16+c];
        AB[tid] = s;
    }
}

// ---------------- K1: GAT1 fused with lin2 (r12 version: 2048 blocks) ----------
__global__ __launch_bounds__(256) void k_gat1f(
    const float* __restrict__ x_seq, const uchar* __restrict__ M0,
    const uchar* __restrict__ M1,
    const float* __restrict__ Wl, const float* __restrict__ Wr,
    const float* __restrict__ att, const float* __restrict__ bias,
    const float* __restrict__ AB,
    const float* __restrict__ Wl2, const float* __restrict__ Wr2,
    const float* __restrict__ att2,
    float* __restrict__ xl2, float* __restrict__ xr2,
    float* __restrict__ ui, float* __restrict__ vj)
{
    __shared__ float x_s[NN];
    __shared__ float S_s[4][4];
    __shared__ float h_s[4][HH];
    __shared__ float Wl2_s[64*64];
    __shared__ float Wr2_s[64*64];
    int bt = blockIdx.y; int t = bt % TT;
    int i0 = blockIdx.x * 4;
    int tid = threadIdx.x;
    int il = tid >> 6, jl = tid & 63;
    int i = i0 + il;
    const uchar* M = t ? M1 : M0;
    ((float2*)x_s)[tid] = ((const float2*)(x_seq + bt*NN))[tid];
    #pragma unroll
    for (int q = 0; q < 4; ++q){
        int idx = q*256 + tid;
        ((float4*)Wl2_s)[idx] = ((const float4*)Wl2)[idx];
        ((float4*)Wr2_s)[idx] = ((const float4*)Wr2)[idx];
    }
    __syncthreads();
    float xi = x_s[i];
    const uchar* Mrow = M + (size_t)i*NN;
    float xj[8], msk[8];
    #pragma unroll
    for (int jj = 0; jj < 8; ++jj){
        int j = jj*64 + jl;
        xj[jj] = x_s[j];
        msk[jj] = Mrow[j] ? 1.f : 0.f;
    }
    float sw[4] = {0,0,0,0}, swx[4] = {0,0,0,0};
    for (int h = 0; h < 4; ++h){
        float acc[8] = {0,0,0,0,0,0,0,0};
        #pragma unroll
        for (int c = 0; c < 16; ++c){
            int hc = h*16 + c;
            float wl = Wl[hc];
            float q  = 0.4f * att[hc];
            float pr = xi * Wr[hc];
            #pragma unroll
            for (int jj = 0; jj < 8; ++jj){
                float s = fmaf(xj[jj], wl, pr);
                acc[jj] = fmaf(q, fabsf(s), acc[jj]);
            }
        }
        float lin = 0.6f * xi * AB[h];
        float al6 = 0.6f * AB[4+h];
        #pragma unroll
        for (int jj = 0; jj < 8; ++jj){
            float e = acc[jj] + fmaf(al6, xj[jj], lin);
            float w = msk[jj] * __expf(e);
            sw[h] += w;
            swx[h] = fmaf(w, xj[jj], swx[h]);
        }
    }
    #pragma unroll
    for (int off = 32; off; off >>= 1){
        #pragma unroll
        for (int h = 0; h < 4; ++h){
            sw[h]  += __shfl_down(sw[h],  off);
            swx[h] += __shfl_down(swx[h], off);
        }
    }
    if (jl == 0){
        #pragma unroll
        for (int h = 0; h < 4; ++h) S_s[il][h] = swx[h] / sw[h];
    }
    __syncthreads();
    {
        int hc = tid & 63, row = tid >> 6;
        float v = S_s[row][hc >> 4] * Wl[hc] + bias[hc];
        h_s[row][hc] = elu1(v);
    }
    __syncthreads();
    {
        int c = tid & 63, row = tid >> 6;
        float al = 0.f, ar = 0.f;
        #pragma unroll 8
        for (int k = 0; k < 64; ++k){
            float hv = h_s[row][k];
            al = fmaf(hv, Wl2_s[k*64 + c], al);
            ar = fmaf(hv, Wr2_s[k*64 + c], ar);
        }
        size_t ridx = (size_t)(bt*NN + i0 + row);
        xl2[ridx*HH + c] = al;
        xr2[ridx*HH + c] = ar;
        float a2 = att2[c];
        float pu = a2 * ar, pv = a2 * al;
        #pragma unroll
        for (int off = 32; off; off >>= 1){
            pu += __shfl_down(pu, off);
            pv += __shfl_down(pv, off);
        }
        if (c == 0){ ui[ridx] = pu; vj[ridx] = pv; }
    }
}

// ---------------- K2: fused GAT2, 8-wave 32-i-tile (r12 version) ---------------
__global__ __launch_bounds__(512) void k_gat2(
    const float* __restrict__ xl2, const float* __restrict__ xr2,
    const uchar* __restrict__ M0, const uchar* __restrict__ M1,
    const float* __restrict__ att, const float* __restrict__ ui,
    const float* __restrict__ vj, const float* __restrict__ bias,
    float* __restrict__ hseq)
{
    __shared__ float xl_s[256][68];   // 69632 B (reused as reduce scratch at end)
    __shared__ float wT_s[256][36];   // 36864 B  wT[j][i_local]
    __shared__ float v_s[256];
    __shared__ float z_s[32];

    int bt = blockIdx.y, t = bt & 7;
    int i0 = blockIdx.x * 32;
    int base = bt * NN;
    int tid = threadIdx.x;
    const uchar* M = t ? M1 : M0;

    int ig = __builtin_amdgcn_readfirstlane(tid >> 6);  // wave id, uniform
    int jg = tid & 63;
    int ln = jg;
    int ig2 = ln >> 3, cg2 = ln & 7;

    const float* xrp0 = xr2 + (size_t)(base + i0 + ig*4 + 0)*HH;
    const float* xrp1 = xr2 + (size_t)(base + i0 + ig*4 + 1)*HH;
    const float* xrp2 = xr2 + (size_t)(base + i0 + ig*4 + 2)*HH;
    const float* xrp3 = xr2 + (size_t)(base + i0 + ig*4 + 3)*HH;
    float u0 = 0.6f*ui[base + i0 + ig*4 + 0];
    float u1 = 0.6f*ui[base + i0 + ig*4 + 1];
    float u2 = 0.6f*ui[base + i0 + ig*4 + 2];
    float u3 = 0.6f*ui[base + i0 + ig*4 + 3];

    float zreg[4] = {0.f,0.f,0.f,0.f};
    float acc[4][8];
    #pragma unroll
    for (int a = 0; a < 4; ++a)
        #pragma unroll
        for (int r = 0; r < 8; ++r) acc[a][r] = 0.f;

    for (int tile = 0; tile < 2; ++tile){
        int j0 = tile * 256;
        __syncthreads();
        #pragma unroll
        for (int q = 0; q < 8; ++q){
            int idx = q*512 + tid;
            int row = idx >> 4, c4 = idx & 15;
            ((float4*)&xl_s[row][0])[c4] = ((const float4*)&xl2[(size_t)(base+j0+row)*HH])[c4];
        }
        if (tid < 256) v_s[tid] = vj[base + j0 + tid];
        __syncthreads();
        float e[4][4];
        #pragma unroll
        for (int jj = 0; jj < 4; ++jj){
            float vv = 0.6f * v_s[jj*64 + jg];
            e[0][jj] = u0 + vv; e[1][jj] = u1 + vv;
            e[2][jj] = u2 + vv; e[3][jj] = u3 + vv;
        }
        #pragma unroll 4
        for (int c4 = 0; c4 < 16; ++c4){
            float4 a4 = *(const float4*)&att[c4*4];
            float qk[4];
            qk[0] = 0.4f*a4.x; qk[1] = 0.4f*a4.y; qk[2] = 0.4f*a4.z; qk[3] = 0.4f*a4.w;
            float rr[4][4];
            *(float4*)rr[0] = *(const float4*)&xrp0[c4*4];
            *(float4*)rr[1] = *(const float4*)&xrp1[c4*4];
            *(float4*)rr[2] = *(const float4*)&xrp2[c4*4];
            *(float4*)rr[3] = *(const float4*)&xrp3[c4*4];
            float xlv[4][4];
            #pragma unroll
            for (int jj = 0; jj < 4; ++jj)
                *(float4*)xlv[jj] = ((const float4*)&xl_s[jj*64+jg][0])[c4];
            #pragma unroll
            for (int jj = 0; jj < 4; ++jj)
                #pragma unroll
                for (int k = 0; k < 4; ++k){
                    float xc = xlv[jj][k];
                    #pragma unroll
                    for (int ii = 0; ii < 4; ++ii)
                        e[ii][jj] = fmaf(qk[k], fabsf(rr[ii][k] + xc), e[ii][jj]);
                }
        }
        #pragma unroll
        for (int jj = 0; jj < 4; ++jj){
            int j = jj*64 + jg;
            const uchar* mp = &M[(size_t)(i0 + ig*4)*NN + j0 + j];
            float w0 = mp[0]      ? __expf(e[0][jj]) : 0.f;
            float w1 = mp[NN]     ? __expf(e[1][jj]) : 0.f;
            float w2 = mp[2*NN]   ? __expf(e[2][jj]) : 0.f;
            float w3 = mp[3*NN]   ? __expf(e[3][jj]) : 0.f;
            zreg[0] += w0; zreg[1] += w1; zreg[2] += w2; zreg[3] += w3;
            float4 wq; wq.x = w0; wq.y = w1; wq.z = w2; wq.w = w3;
            *(float4*)&wT_s[j][ig*4] = wq;
        }
        __syncthreads();
        #pragma unroll 4
        for (int jj = 0; jj < 32; ++jj){
            int j = ig*32 + jj;
            float w4[4], xa[8];
            *(float4*)w4      = *(const float4*)&wT_s[j][ig2*4];
            *(float4*)&xa[0]  = ((const float4*)&xl_s[j][0])[cg2*2+0];
            *(float4*)&xa[4]  = ((const float4*)&xl_s[j][0])[cg2*2+1];
            #pragma unroll
            for (int a = 0; a < 4; ++a)
                #pragma unroll
                for (int r = 0; r < 8; ++r)
                    acc[a][r] = fmaf(w4[a], xa[r], acc[a][r]);
        }
    }
    __syncthreads();
    #pragma unroll
    for (int off = 32; off; off >>= 1){
        #pragma unroll
        for (int ii = 0; ii < 4; ++ii) zreg[ii] += __shfl_down(zreg[ii], off);
    }
    if (jg == 0){
        #pragma unroll
        for (int ii = 0; ii < 4; ++ii) z_s[ig*4+ii] = zreg[ii];
    }
    float* scratch = &xl_s[0][0];   // need 32*448 = 14336 floats < 17408
    if (ig > 0){
        #pragma unroll
        for (int a = 0; a < 4; ++a)
            #pragma unroll
            for (int r = 0; r < 8; ++r)
                scratch[(a*8+r)*448 + (ig-1)*64 + ln] = acc[a][r];
    }
    __syncthreads();
    if (ig == 0){
        float pm[8];
        #pragma unroll
        for (int r = 0; r < 8; ++r) pm[r] = 0.f;
        #pragma unroll
        for (int a = 0; a < 4; ++a){
            float rz = 1.f / z_s[ig2*4 + a];
            #pragma unroll
            for (int r = 0; r < 8; ++r){
                float s = acc[a][r];
                #pragma unroll
                for (int w = 0; w < 7; ++w)
                    s += scratch[(a*8+r)*448 + w*64 + ln];
                float h = elu1(s*rz + bias[cg2*8 + r]);
                pm[r] += h;
            }
        }
        #pragma unroll
        for (int off = 32; off >= 8; off >>= 1){
            #pragma unroll
            for (int r = 0; r < 8; ++r) pm[r] += __shfl_down(pm[r], off);
        }
        if (ig2 == 0){
            #pragma unroll
            for (int r = 0; r < 8; ++r)
                atomicAdd(&hseq[bt*HH + cg2*8 + r], pm[r] * (1.f/(float)NN));
        }
    }
}

// ---------------- K3: GRU x2 — Wih LDS-staged + quad-vectorized (r12) ----------
__global__ __launch_bounds__(256, 1) void k_gru2(
    const float* __restrict__ hseq, const float* __restrict__ Wih0,
    const float* __restrict__ bih0, const float4* __restrict__ WT4,
    const float* __restrict__ bhh0, const float* __restrict__ Wih1,
    const float* __restrict__ bih1, const float* __restrict__ bhh1,
    const float* __restrict__ lamp, const float* __restrict__ attn_W,
    const float* __restrict__ attn_b, const float* __restrict__ W1,
    const float* __restrict__ b1, const float* __restrict__ ln_g,
    const float* __restrict__ ln_b, const float* __restrict__ W2,
    const float* __restrict__ b2, float* __restrict__ out)
{
    __shared__ float wih0_s[64*192];         // 49152 B
    __shared__ float wih1_s[64*192];         // 49152 B
    __shared__ float gi_s[BB*TT*192];        // 12288 B
    __shared__ float hs_s[BB*TT*HH];         // 4096 B
    __shared__ float y_s[BB*TT*HH];          // 4096 B
    __shared__ float part_s[2][BB][2][3][HH];// 6144 B (parity double-buffer)
    __shared__ float sc_s[BB][TT], at_s[BB][TT];
    __shared__ float fin_s[BB][HH], z_s[BB][HH], g_s[BB][HH];
    __shared__ float mu_s[BB], iv_s[BB];
    int tid = threadIdx.x;
    int wave = tid >> 6, ln = tid & 63;
    int b = wave >> 1, half = wave & 1;

    // Issue Wih staging FIRST: 2 x 12 independent coalesced float4 loads/thread.
    #pragma unroll
    for (int i = 0; i < 12; ++i){
        int idx = i*256 + tid;               // 0..3071 float4
        ((float4*)wih0_s)[idx] = ((const float4*)Wih0)[idx];
        ((float4*)wih1_s)[idx] = ((const float4*)Wih1)[idx];
    }
    // layer-0 Whh half-slice -> registers, lane-coalesced (k-major WT4)
    float wx[32], wy[32], wz[32];
    #pragma unroll
    for (int k = 0; k < 32; ++k){
        float4 w4 = WT4[(half*32 + k)*64 + ln];
        wx[k] = w4.x; wy[k] = w4.y; wz[k] = w4.z;
    }
    ((float4*)hs_s)[tid] = ((const float4*)hseq)[tid];   // 1024 floats = 256 f4
    __syncthreads();
    // gi0 = hseq @ Wih0 + bih0 -- quad-vectorized: 768 output-quads, 3/thread
    #pragma unroll
    for (int o = 0; o < 3; ++o){
        int idx4 = o*256 + tid;              // 0..767
        int bt = idx4 / 48, q = idx4 % 48;   // outputs g = 4q..4q+3
        float4 a4 = ((const float4*)bih0)[q];
        const float* hr = &hs_s[bt*HH];
        #pragma unroll 4
        for (int k = 0; k < HH; ++k){
            float hk = hr[k];
            float4 w4 = ((const float4*)&wih0_s[k*192])[q];
            a4.x = fmaf(hk, w4.x, a4.x);
            a4.y = fmaf(hk, w4.y, a4.y);
            a4.z = fmaf(hk, w4.z, a4.z);
            a4.w = fmaf(hk, w4.w, a4.w);
        }
        ((float4*)&gi_s[bt*192])[q] = a4;
    }
    __syncthreads();
    // ---- layer 0: 1 barrier/step ----
    {
        float bhr = bhh0[ln], bhz = bhh0[64+ln], bhn = bhh0[128+ln];
        float h = 0.f;
        for (int t = 0; t < TT; ++t){
            float pr = 0.f, pz = 0.f, pn = 0.f;
            #pragma unroll
            for (int k = 0; k < 32; ++k){
                float hk = __shfl(h, half*32 + k);
                pr = fmaf(wx[k], hk, pr);
                pz = fmaf(wy[k], hk, pz);
                pn = fmaf(wz[k], hk, pn);
            }
            int pc = t & 1;
            part_s[pc][b][half][0][ln] = pr;
            part_s[pc][b][half][1][ln] = pz;
            part_s[pc][b][half][2][ln] = pn;
            __syncthreads();
            float ghr = pr + part_s[pc][b][1-half][0][ln] + bhr;
            float ghz = pz + part_s[pc][b][1-half][1][ln] + bhz;
            float ghn = pn + part_s[pc][b][1-half][2][ln] + bhn;
            const float* gi = &gi_s[(b*TT+t)*192];
            float r = sigm(gi[ln] + ghr);
            float z = sigm(gi[64+ln] + ghz);
            float n = tanhf(gi[128+ln] + r*ghn);
            h = (1.f - z)*n + z*h;
            if (half == 0) y_s[(b*TT+t)*HH + ln] = h;
        }
    }
    // reload Whh weights for layer 1 (coalesced)
    #pragma unroll
    for (int k = 0; k < 32; ++k){
        float4 w4 = WT4[4096 + (half*32 + k)*64 + ln];
        wx[k] = w4.x; wy[k] = w4.y; wz[k] = w4.z;
    }
    __syncthreads();                          // y_s complete
    // gi1 = y @ Wih1 + bih1 -- quad-vectorized
    #pragma unroll
    for (int o = 0; o < 3; ++o){
        int idx4 = o*256 + tid;
        int bt = idx4 / 48, q = idx4 % 48;
        float4 a4 = ((const float4*)bih1)[q];
        const float* yr = &y_s[bt*HH];
        #pragma unroll 4
        for (int k = 0; k < HH; ++k){
            float yk = yr[k];
            float4 w4 = ((const float4*)&wih1_s[k*192])[q];
            a4.x = fmaf(yk, w4.x, a4.x);
            a4.y = fmaf(yk, w4.y, a4.y);
            a4.z = fmaf(yk, w4.z, a4.z);
            a4.w = fmaf(yk, w4.w, a4.w);
        }
        ((float4*)&gi_s[bt*192])[q] = a4;
    }
    __syncthreads();
    // ---- layer 1: 1 barrier/step ----
    {
        float bhr = bhh1[ln], bhz = bhh1[64+ln], bhn = bhh1[128+ln];
        float h = 0.f;
        for (int t = 0; t < TT; ++t){
            float pr = 0.f, pz = 0.f, pn = 0.f;
            #pragma unroll
            for (int k = 0; k < 32; ++k){
                float hk = __shfl(h, half*32 + k);
                pr = fmaf(wx[k], hk, pr);
                pz = fmaf(wy[k], hk, pz);
                pn = fmaf(wz[k], hk, pn);
            }
            int pc = t & 1;
            part_s[pc][b][half][0][ln] = pr;
            part_s[pc][b][half][1][ln] = pz;
            part_s[pc][b][half][2][ln] = pn;
            __syncthreads();
            float ghr = pr + part_s[pc][b][1-half][0][ln] + bhr;
            float ghz = pz + part_s[pc][b][1-half][1][ln] + bhz;
            float ghn = pn + part_s[pc][b][1-half][2][ln] + bhn;
            const float* gi = &gi_s[(b*TT+t)*192];
            float r = sigm(gi[ln] + ghr);
            float z = sigm(gi[64+ln] + ghz);
            float n = tanhf(gi[128+ln] + r*ghn);
            h = (1.f - z)*n + z*h;
            if (half == 0) y_s[(b*TT+t)*HH + ln] = h;
        }
    }
    __syncthreads();
    // ---- head ----
    float lam = fmaxf(lamp[0], 0.01f);
    if (tid < TT) out[BB*NC + tid] = expf(-lam*(float)tid);
    if (tid < BB*TT){
        int bb = tid >> 3, t = tid & 7;
        float s = attn_b[0];
        const float* r = &y_s[(bb*TT+t)*HH];
        for (int h = 0; h < HH; ++h) s += r[h]*attn_W[h];
        sc_s[bb][t] = s;
    }
    __syncthreads();
    if (tid < BB){
        float mx = -INFINITY;
        for (int t = 0; t < TT; ++t) mx = fmaxf(mx, sc_s[tid][t]);
        float se = 0.f;
        for (int t = 0; t < TT; ++t){ float w = expf(sc_s[tid][t]-mx); at_s[tid][t] = w; se += w; }
        for (int t = 0; t < TT; ++t){
            at_s[tid][t] /= se;
            out[BB*NC + TT + tid*TT + t] = at_s[tid][t];
        }
    }
    __syncthreads();
    if (tid < BB*HH){
        int bb = tid >> 6, h = tid & 63;
        float a = 0.f;
        for (int t = 0; t < TT; ++t) a += at_s[bb][t]*y_s[(bb*TT+t)*HH + h];
        fin_s[bb][h] = a;
    }
    __syncthreads();
    if (tid < BB*HH){
        int bb = tid >> 6, h = tid & 63;
        float a = b1[h];
        for (int k = 0; k < HH; ++k) a += fin_s[bb][k]*W1[k*HH+h];
        z_s[bb][h] = a;
    }
    __syncthreads();
    if (tid < BB){
        float mu = 0.f;
        for (int h = 0; h < HH; ++h) mu += z_s[tid][h];
        mu *= (1.f/HH);
        float v = 0.f;
        for (int h = 0; h < HH; ++h){ float d = z_s[tid][h]-mu; v += d*d; }
        v *= (1.f/HH);
        mu_s[tid] = mu; iv_s[tid] = 1.f/sqrtf(v + 1e-5f);
    }
    __syncthreads();
    if (tid < BB*HH){
        int bb = tid >> 6, h = tid & 63;
        float zn = (z_s[bb][h]-mu_s[bb])*iv_s[bb]*ln_g[h] + ln_b[h];
        g_s[bb][h] = 0.5f*zn*(1.f + erff(zn*0.70710678118654752f));
    }
    __syncthreads();
    if (tid < BB*NC){
        int bb = tid / NC, c = tid % NC;
        float a = b2[c];
        for (int k = 0; k < HH; ++k) a += g_s[bb][k]*W2[k*NC+c];
        out[bb*NC + c] = a;
    }
}

extern "C" void kernel_launch(void* const* d_in, const int* in_sizes, int n_in,
                              void* d_out, int out_size, void* d_ws, size_t ws_size,
                              hipStream_t stream)
{
    const float* x_seq = (const float*)d_in[0];
    const float* sadj  = (const float*)d_in[1];
    const float* dynW  = (const float*)d_in[2];
    const float* lamp  = (const float*)d_in[3];
    const float* g1_Wl = (const float*)d_in[4];
    const float* g1_Wr = (const float*)d_in[5];
    const float* g1_att= (const float*)d_in[6];
    const float* g1_b  = (const float*)d_in[7];
    const float* g2_Wl = (const float*)d_in[8];
    const float* g2_Wr = (const float*)d_in[9];
    const float* g2_att= (const float*)d_in[10];
    const float* g2_b  = (const float*)d_in[11];
    const float* Wih0  = (const float*)d_in[12];
    const float* Whh0  = (const float*)d_in[13];
    const float* bih0  = (const float*)d_in[14];
    const float* bhh0  = (const float*)d_in[15];
    const float* Wih1  = (const float*)d_in[16];
    const float* Whh1  = (const float*)d_in[17];
    const float* bih1  = (const float*)d_in[18];
    const float* bhh1  = (const float*)d_in[19];
    const float* attnW = (const float*)d_in[20];
    const float* attnb = (const float*)d_in[21];
    const float* W1    = (const float*)d_in[22];
    const float* b1    = (const float*)d_in[23];
    const float* lng   = (const float*)d_in[24];
    const float* lnb   = (const float*)d_in[25];
    const float* W2    = (const float*)d_in[26];
    const float* b2    = (const float*)d_in[27];
    float* out = (float*)d_out;

    const int RWS = BB*TT*NN*HH;              // 524288
    uchar* M0 = (uchar*)d_ws;                 // 262144 B
    uchar* M1 = M0 + (size_t)NN*NN;           // 262144 B
    float* fb = (float*)(M1 + (size_t)NN*NN);
    float* AB   = fb;                         // 16
    float* ui   = AB   + 16;                  // 8192
    float* vj   = ui   + BB*TT*NN;            // 8192
    float* xl2  = vj   + BB*TT*NN;            // 524288
    float* xr2  = xl2  + RWS;                 // 524288
    float* hseq = xr2  + RWS;                 // 1024
    float4* WT4 = (float4*)(hseq + BB*TT*HH); // 2*4096 float4 = 131072 B
    // total ~4.8 MB

    k_mask <<<dim3(8,8,2), 256, 0, stream>>>(dynW, sadj, M0, M1, hseq, g1_att, g1_Wr, g1_Wl, AB,
                                             Whh0, Whh1, WT4);
    k_gat1f<<<dim3(NN/4, BB*TT), 256, 0, stream>>>(x_seq, M0, M1, g1_Wl, g1_Wr, g1_att, g1_b, AB,
                                                   g2_Wl, g2_Wr, g2_att, xl2, xr2, ui, vj);
    k_gat2 <<<dim3(NN/32, BB*TT), 512, 0, stream>>>(xl2, xr2, M0, M1, g2_att, ui, vj, g2_b, hseq);
    k_gru2 <<<1, 256, 0, stream>>>(hseq, Wih0, bih0, WT4, bhh0, Wih1, bih1, bhh1,
                                   lamp, attnW, attnb, W1, b1, lng, lnb, W2, b2, out);
}